// Round 6
// baseline (269.600 us; speedup 1.0000x reference)
//
#include <hip/hip_runtime.h>
#include <math.h>

#define NB 2048
#define NV 110
#define NH1 5
#define NF1 24
#define NH2 3
#define NF2 3
#define C1 (NH1*NF1)   // 120
#define LALPHA 0.2f

constexpr int NN = NV*NV;          // 12100
constexpr int T1 = 512;
constexpr int KP = 136;            // padded K stride (halves)
constexpr int W1ROWS = 144;        // 120 feat cols + pad + 10 logit cols + pad

typedef _Float16 f16;
typedef f16  f16x8 __attribute__((ext_vector_type(8)));
typedef f16  f16x4 __attribute__((ext_vector_type(4)));
typedef float f32x4 __attribute__((ext_vector_type(4)));

__device__ __forceinline__ f32x4 mfma16(f16x8 a, f16x8 b, f32x4 c) {
  return __builtin_amdgcn_mfma_f32_16x16x32_f16(a, b, c, 0, 0, 0);
}
__device__ __forceinline__ float lrelu(float x){ return x > 0.f ? x : LALPHA*x; }
__device__ __forceinline__ float sigm(float x){ return 1.f/(1.f+__expf(-x)); }
__device__ __forceinline__ float wmax(float v){
  #pragma unroll
  for (int d=32; d; d>>=1) v = fmaxf(v, __shfl_xor(v,d));
  return v;
}
__device__ __forceinline__ float wsum(float v){
  #pragma unroll
  for (int d=32; d; d>>=1) v += __shfl_xor(v,d);
  return v;
}
__device__ __forceinline__ f32x4 ld4u(const float* p){
  f32x4 v; __builtin_memcpy(&v, p, 16); return v;
}

// ---- Kernel 0: precompute sigmoid(M), augmented W1^T, augmented W2^T ----
// W1tg rows: 0..119 = W1^T cat; 128+h = es-col head h; 133+h = en-col; rest 0
// W2tg rows: 0..8 = W2^T cat; 9+g = es2-col; 12+g = en2-col; 15 = 0
__global__ void precomp_kernel(const float* __restrict__ M, const float* __restrict__ W1,
                               const float* __restrict__ as1, const float* __restrict__ an1,
                               const float* __restrict__ W2, const float* __restrict__ as2,
                               const float* __restrict__ an2,
                               float* __restrict__ Msig, f16* __restrict__ W1tg,
                               f16* __restrict__ W2tg) {
  const int i = blockIdx.x*256 + threadIdx.x;
  if (i < NN) {
    Msig[i] = sigm(M[i]);
  } else if (i < NN + W1ROWS*KP) {
    const int j = i - NN, f = j/KP, k = j%KP;
    float v = 0.f;
    if (k < NV) {
      if (f < C1) {
        v = W1[(f/NF1)*(NV*NF1) + k*NF1 + (f%NF1)];
      } else if (f >= 128 && f < 133) {
        const int h = f - 128;
        for (int ff = 0; ff < NF1; ++ff)
          v += W1[h*(NV*NF1) + k*NF1 + ff] * as1[h*NF1 + ff];
      } else if (f >= 133 && f < 138) {
        const int h = f - 133;
        for (int ff = 0; ff < NF1; ++ff)
          v += W1[h*(NV*NF1) + k*NF1 + ff] * an1[h*NF1 + ff];
      }
    }
    W1tg[f*KP + k] = (f16)v;
  } else if (i < NN + W1ROWS*KP + 16*KP) {
    const int j = i - NN - W1ROWS*KP, r = j/KP, k = j%KP;
    float v = 0.f;
    if (k < C1) {
      if (r < 9) {
        v = W2[(r/NF2)*(C1*NF2) + k*NF2 + (r%NF2)];
      } else if (r < 12) {
        const int g = r - 9;
        for (int f2 = 0; f2 < NF2; ++f2)
          v += W2[g*(C1*NF2) + k*NF2 + f2] * as2[g*NF2 + f2];
      } else if (r < 15) {
        const int g = r - 12;
        for (int f2 = 0; f2 < NF2; ++f2)
          v += W2[g*(C1*NF2) + k*NF2 + f2] * an2[g*NF2 + f2];
      }
    }
    W2tg[r*KP + k] = (f16)v;
  }
}

// ---- fully fused GAT: layer1 + layer2 + readout, one block per batch ----
__global__ __launch_bounds__(T1, 4) void gat_fused(
  const float* __restrict__ X, const float* __restrict__ A,
  const float* __restrict__ Msig, const f16* __restrict__ W1tg,
  const float* __restrict__ b1,  const f16* __restrict__ W2tg,
  const float* __restrict__ b2,  const float* __restrict__ fc1w,
  const float* __restrict__ fc2w, float* __restrict__ out)
{
  // LDS = 30464+34816+4352+2240+2240+1760+3584 = 79,456 B  (2 blocks/CU)
  __shared__ __attribute__((aligned(16))) f16 sXm [112*KP]; // Xm / P1 / h1 / P2(even)
  __shared__ __attribute__((aligned(16))) f16 sFt [128*KP]; // feats^T / P2(odd)
  __shared__ __attribute__((aligned(16))) f16 sF2t[16*KP];  // feats2^T
  __shared__ float sES[NH1*112];
  __shared__ float sEN[NH1*112];
  __shared__ unsigned long long sAM[2*NV];
  __shared__ float sCMBf[8*112];        // expsum per (head, row); heads 0..4 L1, 5..7 L2

  const int b = blockIdx.x, tid = threadIdx.x;
  const int wave = tid >> 6, lane = tid & 63;
  const int lr = lane & 15, lh = lane >> 4;
  const float* __restrict__ Xb = X + (size_t)b*NN;
  const float* __restrict__ Ab = A + (size_t)b*NN;

  float* const sT = sES;          // aliases, used only in the final phase
  float* const sS = sES + 112;

  // --- pad-only zero init (disjoint from staged region -> no extra barrier) ---
  // sXm rows 0..109: cols 110..135 ; rows 110,111 full
  for (int n = tid; n < 110; n += T1) {
    *(unsigned*)&sXm[n*KP + 110] = 0u;
    *(uint4*)&sXm[n*KP + 112] = uint4{0,0,0,0};
    *(uint4*)&sXm[n*KP + 120] = uint4{0,0,0,0};
    *(uint4*)&sXm[n*KP + 128] = uint4{0,0,0,0};
  }
  for (int i = tid; i < 2*KP/8; i += T1) ((uint4*)&sXm[110*KP])[i] = uint4{0,0,0,0};
  // sFt all rows: cols 112..135 (feats/P2 writes cover cols 0..111)
  for (int n = tid; n < 128; n += T1) {
    *(uint4*)&sFt[n*KP + 112] = uint4{0,0,0,0};
    *(uint4*)&sFt[n*KP + 120] = uint4{0,0,0,0};
    *(uint4*)&sFt[n*KP + 128] = uint4{0,0,0,0};
  }
  // sF2t entirely
  for (int i = tid; i < (16*KP)/8; i += T1) ((uint4*)sF2t)[i] = uint4{0,0,0,0};
  // expsum accumulators
  for (int i = tid; i < 8*112; i += T1) sCMBf[i] = 0.f;

  // --- stage Xm = X * Msig (float4 loads), adjacency ballot ---
  for (int t = tid; t < NV*28; t += T1) {
    const int n = t/28, c = t%28, k = 4*c;
    if (c < 27) {
      f32x4 x = ld4u(Xb + n*NV + k);
      f32x4 m = ld4u(Msig + n*NV + k);
      f16x4 v;
      #pragma unroll
      for (int j = 0; j < 4; ++j) v[j] = (f16)(x[j]*m[j]);
      *(f16x4*)&sXm[n*KP + k] = v;
    } else {
      sXm[n*KP + 108] = (f16)(Xb[n*NV+108]*Msig[n*NV+108]);
      sXm[n*KP + 109] = (f16)(Xb[n*NV+109]*Msig[n*NV+109]);
    }
  }
  for (int n = wave; n < NV; n += 8) {
    unsigned long long m0 = __ballot(Ab[n*NV + lane] > 0.f);
    const int mm = 64 + lane;
    unsigned long long m1 = __ballot((mm < NV) && (Ab[n*NV + mm] > 0.f));
    if (lane == 0) { sAM[2*n] = m0; sAM[2*n+1] = m1; }
  }
  // W1 B-fragments straight from global (L2-resident, zero-padded)
  f16x8 bW[4], bL[4];
  #pragma unroll
  for (int k = 0; k < 4; ++k)
    bW[k] = *(const f16x8*)&W1tg[(wave*16 + lr)*KP + k*32 + lh*8];
  if (wave < 2) {
    #pragma unroll
    for (int k = 0; k < 4; ++k)
      bL[k] = *(const f16x8*)&W1tg[(128 + lr)*KP + k*32 + lh*8];
  }
  __syncthreads();

  // --- GEMM1: feats = Xm @ W1cat ; wave w -> f-tile w ; waves 0,1 logits ---
  #pragma unroll
  for (int m = 0; m < 7; ++m) {
    f32x4 acc = {0.f,0.f,0.f,0.f};
    #pragma unroll
    for (int k = 0; k < 4; ++k) {
      f16x8 af = *(const f16x8*)&sXm[(m*16 + lr)*KP + k*32 + lh*8];
      acc = mfma16(af, bW[k], acc);
    }
    f16x4 v;
    #pragma unroll
    for (int r = 0; r < 4; ++r) v[r] = (f16)acc[r];
    *(f16x4*)&sFt[(wave*16 + lr)*KP + m*16 + lh*4] = v;   // sFt[f][m]
  }
  if (wave < 2) {   // logit tile split: wave0 m0..3, wave1 m4..6
    const int mlo = wave ? 4 : 0, mhi = wave ? 7 : 4;
    for (int m = mlo; m < mhi; ++m) {
      f32x4 acc = {0.f,0.f,0.f,0.f};
      #pragma unroll
      for (int k = 0; k < 4; ++k) {
        f16x8 af = *(const f16x8*)&sXm[(m*16 + lr)*KP + k*32 + lh*8];
        acc = mfma16(af, bL[k], acc);
      }
      const int mg0 = m*16 + lh*4;
      if (lr < 5)       *(f32x4*)&sES[lr*112 + mg0] = acc;
      else if (lr < 10) *(f32x4*)&sEN[(lr-5)*112 + mg0] = acc;
    }
  }
  __syncthreads();

  // --- balanced masked-softmax sweep: 110 rows x 14 col-chunks flat ---
  auto sweep = [&](const float* __restrict__ esr, const float* __restrict__ enr,
                   float* __restrict__ cmb, f16* __restrict__ dst) {
    for (int t = tid; t < 110*14; t += T1) {
      const int c8 = t/110, n = t - c8*110;    // consecutive lanes -> consecutive n
      const int m0 = c8*8;
      const float es = esr[n];
      const f32x4 enA = *(const f32x4*)&enr[m0];
      const f32x4 enB = *(const f32x4*)&enr[m0+4];
      const unsigned bits = (unsigned)(sAM[2*n + (m0>>6)] >> (m0 & 63)) & 0xFFu;
      float ev[8]; float ps = 0.f;
      #pragma unroll
      for (int j = 0; j < 8; ++j) {
        float v = es + ((j < 4) ? enA[j] : enB[j-4]);
        v = fmaxf(v, LALPHA*v);                              // leaky_relu
        float ee = exp2f(fmaf(v, 1.442695041f, -5.770780163f)); // exp(v-4)
        ee = (bits & (1u << j)) ? ee : 0.f;                  // adjacency mask
        ps += ee; ev[j] = ee;
      }
      f16x8 pk;
      #pragma unroll
      for (int j = 0; j < 8; ++j) pk[j] = (f16)ev[j];
      *(f16x8*)&dst[n*KP + m0] = pk;
      atomicAdd(&cmb[n], ps);
    }
  };

  // --- 5 layer-1 head passes ---
  const int nt = wave & 1, mh = wave >> 1;
  f16 h1r[5][2][4];
  #pragma unroll
  for (int p = 0; p < 5; ++p) {
    sweep(&sES[p*112], &sEN[p*112], &sCMBf[p*112], sXm);
    __syncthreads();
    // GEMM2: h_p = Pnorm @ feats_p ; normalization folded into epilogue
    f16x8 bf[4];
    #pragma unroll
    for (int k = 0; k < 4; ++k)
      bf[k] = *(const f16x8*)&sFt[(p*NF1 + nt*16 + lr)*KP + k*32 + lh*8];
    const int fl = nt*16 + lr;
    const float bv = (fl < NF1) ? b1[fl] : 0.f;
    #pragma unroll
    for (int mi = 0; mi < 2; ++mi) {
      const int m = 2*mh + mi;
      if (m < 7) {
        f32x4 acc = {0.f,0.f,0.f,0.f};
        #pragma unroll
        for (int k = 0; k < 4; ++k) {
          f16x8 af = *(const f16x8*)&sXm[(m*16 + lr)*KP + k*32 + lh*8];
          acc = mfma16(af, bf[k], acc);
        }
        const int mg0 = m*16 + lh*4;
        const f32x4 cmv = *(const f32x4*)&sCMBf[p*112 + mg0];
        #pragma unroll
        for (int r = 0; r < 4; ++r)
          h1r[p][mi][r] = (f16)lrelu(acc[r]*(1.f/cmv[r]) + bv);
      }
    }
    __syncthreads();
  }

  // --- dump h1 regs -> sXm[n][c] ---
  {
    const int fl = nt*16 + lr;
    if (fl < NF1) {
      #pragma unroll
      for (int p = 0; p < 5; ++p) {
        #pragma unroll
        for (int mi = 0; mi < 2; ++mi) {
          const int m = 2*mh + mi;
          if (m < 7) {
            #pragma unroll
            for (int r = 0; r < 4; ++r) {
              const int mg = m*16 + lh*4 + r;
              if (mg < NV) sXm[mg*KP + p*NF1 + fl] = h1r[p][mi][r];
            }
          }
        }
      }
    }
  }
  __syncthreads();

  // --- feats2 = h1 @ W2aug : cols 0..8 feats2, cols 9..14 logits ---
  if (wave < 7) {
    f16x8 bW2[4];
    #pragma unroll
    for (int k = 0; k < 4; ++k)
      bW2[k] = *(const f16x8*)&W2tg[lr*KP + k*32 + lh*8];
    f32x4 acc = {0.f,0.f,0.f,0.f};
    #pragma unroll
    for (int k = 0; k < 4; ++k) {
      f16x8 af = *(const f16x8*)&sXm[(wave*16 + lr)*KP + k*32 + lh*8];
      acc = mfma16(af, bW2[k], acc);
    }
    const int mg0 = wave*16 + lh*4;
    if (lr < 9) {
      #pragma unroll
      for (int r = 0; r < 4; ++r) {
        const int mg = mg0 + r;
        if (mg < NV) sF2t[lr*KP + mg] = (f16)acc[r];
      }
    } else if (lr < 12) {
      *(f32x4*)&sES[(lr-9)*112 + mg0] = acc;
    } else if (lr < 15) {
      *(f32x4*)&sEN[(lr-12)*112 + mg0] = acc;
    }
  }
  __syncthreads();

  // --- layer-2: pipelined sweep/GEMM3 with alternating P2 buffers ---
  auto gemm3 = [&](const f16* __restrict__ Pb, int g, f32x4& acc) {
    if (wave < 7) {
      const int brow = (lr < NF2) ? (g*NF2 + lr) : 15;   // row 15 stays zero
      f16x8 bf2[4];
      #pragma unroll
      for (int k = 0; k < 4; ++k)
        bf2[k] = *(const f16x8*)&sF2t[brow*KP + k*32 + lh*8];
      #pragma unroll
      for (int k = 0; k < 4; ++k) {
        f16x8 af = *(const f16x8*)&Pb[(wave*16 + lr)*KP + k*32 + lh*8];
        acc = mfma16(af, bf2[k], acc);
      }
    }
  };

  f32x4 acc2_0 = {0.f,0.f,0.f,0.f};
  f32x4 acc2_1 = {0.f,0.f,0.f,0.f};
  f32x4 acc2_2 = {0.f,0.f,0.f,0.f};
  sweep(&sES[0],   &sEN[0],   &sCMBf[5*112], sXm);
  __syncthreads();
  gemm3(sXm, 0, acc2_0);
  sweep(&sES[112], &sEN[112], &sCMBf[6*112], sFt);
  __syncthreads();
  gemm3(sFt, 1, acc2_1);
  sweep(&sES[224], &sEN[224], &sCMBf[7*112], sXm);
  __syncthreads();
  gemm3(sXm, 2, acc2_2);
  __syncthreads();

  // --- t[n] = sigmoid( lrelu(mean_g(acc2_g/sum_g) + b2) . fc1 ) ---
  if (wave < 7) {
    const int mg0 = wave*16 + lh*4;
    const float fcv = (lr < NF2) ? fc1w[lr] : 0.f;
    const float b2v = (lr < NF2) ? b2[lr]  : 0.f;
    const f32x4 cm0 = *(const f32x4*)&sCMBf[5*112 + mg0];
    const f32x4 cm1 = *(const f32x4*)&sCMBf[6*112 + mg0];
    const f32x4 cm2 = *(const f32x4*)&sCMBf[7*112 + mg0];
    #pragma unroll
    for (int r = 0; r < 4; ++r) {
      const int mg = mg0 + r;
      const float hsum = acc2_0[r]*(1.f/cm0[r]) + acc2_1[r]*(1.f/cm1[r])
                       + acc2_2[r]*(1.f/cm2[r]);
      float hv = (lr < NF2) ? lrelu(hsum*(1.f/NH2) + b2v)*fcv : 0.f;
      hv += __shfl_xor(hv, 1);
      hv += __shfl_xor(hv, 2);
      hv += __shfl_xor(hv, 4);
      hv += __shfl_xor(hv, 8);
      if (lr == 0 && mg < NV) sT[mg] = sigm(hv);
    }
  }
  __syncthreads();
  // --- s = t @ fc2 ---
  if (tid < NV) {
    float acc = 0.f;
    for (int n = 0; n < NV; ++n) acc += sT[n]*fc2w[n*NV + tid];
    sS[tid] = acc;
  }
  __syncthreads();
  // --- out[b] = sum_m t[m]*softmax(s)[m] ---
  if (wave == 0) {
    const float s0 = sS[lane];
    const float s1 = (64+lane < NV) ? sS[64+lane] : -1e38f;
    const float mx = wmax(fmaxf(s0, s1));
    const float p0 = __expf(s0 - mx);
    const float p1 = (64+lane < NV) ? __expf(s1 - mx) : 0.f;
    const float sum = wsum(p0 + p1);
    float val = sT[lane]*p0 + ((64+lane < NV) ? sT[64+lane]*p1 : 0.f);
    val = wsum(val);
    if (lane == 0) out[b] = val/sum;
  }
}

extern "C" void kernel_launch(void* const* d_in, const int* in_sizes, int n_in,
                              void* d_out, int out_size, void* d_ws, size_t ws_size,
                              hipStream_t stream) {
  const float* X   = (const float*)d_in[0];
  const float* A   = (const float*)d_in[1];
  const float* M   = (const float*)d_in[2];
  const float* W1  = (const float*)d_in[3];
  const float* as1 = (const float*)d_in[4];
  const float* an1 = (const float*)d_in[5];
  const float* b1  = (const float*)d_in[6];
  const float* W2  = (const float*)d_in[7];
  const float* as2 = (const float*)d_in[8];
  const float* an2 = (const float*)d_in[9];
  const float* b2  = (const float*)d_in[10];
  const float* fc1 = (const float*)d_in[11];
  const float* fc2 = (const float*)d_in[12];
  float* out = (float*)d_out;

  // ws: Msig f32[12100] | W1tg f16[144*136] | W2tg f16[16*136]
  float* Msig = (float*)d_ws;
  f16* W1tg = (f16*)((char*)d_ws + 48400);
  f16* W2tg = (f16*)((char*)d_ws + 48400 + W1ROWS*KP*2);

  const int pre_items = NN + W1ROWS*KP + 16*KP;
  precomp_kernel<<<(pre_items + 255)/256, 256, 0, stream>>>(
      M, W1, as1, an1, W2, as2, an2, Msig, W1tg, W2tg);
  gat_fused<<<NB, T1, 0, stream>>>(X, A, Msig, W1tg, b1, W2tg,
                                   b2, fc1, fc2, out);
}

// Round 7
// 178.808 us; speedup vs baseline: 1.5078x; 1.5078x over previous
//
#include <hip/hip_runtime.h>
#include <math.h>

#define NB 2048
#define NV 110
#define NH1 5
#define NF1 24
#define NH2 3
#define NF2 3
#define C1 (NH1*NF1)   // 120
#define LALPHA 0.2f

constexpr int NN = NV*NV;          // 12100
constexpr int T1 = 512;
constexpr int KP = 136;            // padded K stride (halves)
constexpr int W1ROWS = 144;        // 120 feat cols + pad + 10 logit cols + pad

typedef _Float16 f16;
typedef f16  f16x8 __attribute__((ext_vector_type(8)));
typedef f16  f16x4 __attribute__((ext_vector_type(4)));
typedef float f32x4 __attribute__((ext_vector_type(4)));

__device__ __forceinline__ f32x4 mfma16(f16x8 a, f16x8 b, f32x4 c) {
  return __builtin_amdgcn_mfma_f32_16x16x32_f16(a, b, c, 0, 0, 0);
}
__device__ __forceinline__ float lrelu(float x){ return x > 0.f ? x : LALPHA*x; }
__device__ __forceinline__ float frcp(float x){ return __builtin_amdgcn_rcpf(x); }
__device__ __forceinline__ float sigm(float x){ return frcp(1.f+__expf(-x)); }
// exp(v-4) as a single fma + hw exp2
__device__ __forceinline__ float expm4(float v){
  return __builtin_amdgcn_exp2f(fmaf(v, 1.442695041f, -5.770780163f));
}
__device__ __forceinline__ float wmax(float v){
  #pragma unroll
  for (int d=32; d; d>>=1) v = fmaxf(v, __shfl_xor(v,d));
  return v;
}
__device__ __forceinline__ float wsum(float v){
  #pragma unroll
  for (int d=32; d; d>>=1) v += __shfl_xor(v,d);
  return v;
}
__device__ __forceinline__ f32x4 ld4u(const float* p){
  f32x4 v; __builtin_memcpy(&v, p, 16); return v;
}

// ---- Kernel 0: precompute sigmoid(M), augmented W1^T, augmented W2^T, fc2^T ----
// W1tg rows: 0..119 = W1^T cat; 128+h = es-col head h; 133+h = en-col; rest 0
// W2tg rows: 0..8 = W2^T cat; 9+g = es2-col; 12+g = en2-col; 15 = 0
// fc2tg rows j=0..111: fc2tg[j][k] = fc2[k][j] (f16, zero-padded)
__global__ void precomp_kernel(const float* __restrict__ M, const float* __restrict__ W1,
                               const float* __restrict__ as1, const float* __restrict__ an1,
                               const float* __restrict__ W2, const float* __restrict__ as2,
                               const float* __restrict__ an2, const float* __restrict__ fc2w,
                               float* __restrict__ Msig, f16* __restrict__ W1tg,
                               f16* __restrict__ W2tg, f16* __restrict__ fc2tg) {
  const int i = blockIdx.x*256 + threadIdx.x;
  if (i < NN) {
    Msig[i] = sigm(M[i]);
  } else if (i < NN + W1ROWS*KP) {
    const int j = i - NN, f = j/KP, k = j%KP;
    float v = 0.f;
    if (k < NV) {
      if (f < C1) {
        v = W1[(f/NF1)*(NV*NF1) + k*NF1 + (f%NF1)];
      } else if (f >= 128 && f < 133) {
        const int h = f - 128;
        for (int ff = 0; ff < NF1; ++ff)
          v += W1[h*(NV*NF1) + k*NF1 + ff] * as1[h*NF1 + ff];
      } else if (f >= 133 && f < 138) {
        const int h = f - 133;
        for (int ff = 0; ff < NF1; ++ff)
          v += W1[h*(NV*NF1) + k*NF1 + ff] * an1[h*NF1 + ff];
      }
    }
    W1tg[f*KP + k] = (f16)v;
  } else if (i < NN + W1ROWS*KP + 16*KP) {
    const int j = i - NN - W1ROWS*KP, r = j/KP, k = j%KP;
    float v = 0.f;
    if (k < C1) {
      if (r < 9) {
        v = W2[(r/NF2)*(C1*NF2) + k*NF2 + (r%NF2)];
      } else if (r < 12) {
        const int g = r - 9;
        for (int f2 = 0; f2 < NF2; ++f2)
          v += W2[g*(C1*NF2) + k*NF2 + f2] * as2[g*NF2 + f2];
      } else if (r < 15) {
        const int g = r - 12;
        for (int f2 = 0; f2 < NF2; ++f2)
          v += W2[g*(C1*NF2) + k*NF2 + f2] * an2[g*NF2 + f2];
      }
    }
    W2tg[r*KP + k] = (f16)v;
  } else if (i < NN + W1ROWS*KP + 16*KP + 112*KP) {
    const int j = i - NN - W1ROWS*KP - 16*KP, col = j/KP, k = j%KP;
    float v = 0.f;
    if (col < NV && k < NV) v = fc2w[k*NV + col];
    fc2tg[col*KP + k] = (f16)v;
  }
}

// ---- fully fused GAT: layer1 + layer2 + readout, one block per batch ----
__global__ __launch_bounds__(T1, 4) void gat_fused(
  const float* __restrict__ X, const float* __restrict__ A,
  const float* __restrict__ Msig, const f16* __restrict__ W1tg,
  const float* __restrict__ b1,  const f16* __restrict__ W2tg,
  const float* __restrict__ b2,  const float* __restrict__ fc1w,
  const f16* __restrict__ fc2tg, float* __restrict__ out)
{
  // LDS = 30464+34816+4352+2240+2240+1760+5376 = 81,248 B  (2 blocks/CU)
  __shared__ __attribute__((aligned(16))) f16 sXm [112*KP]; // Xm / P1 / h1 / P2(even)
  __shared__ __attribute__((aligned(16))) f16 sFt [128*KP]; // feats^T / P2(odd)
  __shared__ __attribute__((aligned(16))) f16 sF2t[16*KP];  // feats2^T / t16
  __shared__ float sES[NH1*112];
  __shared__ float sEN[NH1*112];
  __shared__ unsigned long long sAM[2*NV];
  __shared__ float sCMB[3][112][4];     // partial expsums [slot][row][quarter]

  const int b = blockIdx.x, tid = threadIdx.x;
  const int wave = tid >> 6, lane = tid & 63;
  const int lr = lane & 15, lh = lane >> 4;
  const float* __restrict__ Xb = X + (size_t)b*NN;
  const float* __restrict__ Ab = A + (size_t)b*NN;

  float* const sT = sES;          // aliases, used only in the final phase
  float* const sS = sES + 112;
  f16*   const t16 = sF2t;        // alias: t replicated rows (readout MFMA)

  // --- zero-init (pads must be 0 for MFMA tails) ---
  for (int i = tid; i < (112*KP)/8; i += T1) ((uint4*)sXm )[i] = uint4{0,0,0,0};
  for (int i = tid; i < (128*KP)/8; i += T1) ((uint4*)sFt )[i] = uint4{0,0,0,0};
  for (int i = tid; i < (16*KP)/8;  i += T1) ((uint4*)sF2t)[i] = uint4{0,0,0,0};
  __syncthreads();

  // --- stage Xm = X * Msig (float4 loads), adjacency ballot ---
  for (int t = tid; t < NV*28; t += T1) {
    const int n = t/28, c = t%28, k = 4*c;
    if (c < 27) {
      f32x4 x = ld4u(Xb + n*NV + k);
      f32x4 m = ld4u(Msig + n*NV + k);
      f16x4 v;
      #pragma unroll
      for (int j = 0; j < 4; ++j) v[j] = (f16)(x[j]*m[j]);
      *(f16x4*)&sXm[n*KP + k] = v;
    } else {
      sXm[n*KP + 108] = (f16)(Xb[n*NV+108]*Msig[n*NV+108]);
      sXm[n*KP + 109] = (f16)(Xb[n*NV+109]*Msig[n*NV+109]);
    }
  }
  #pragma unroll
  for (int i = 0; i < 14; ++i) {
    const int n = wave + 8*i;                       // wave-uniform
    if (n < NV) {
      unsigned long long m0 = __ballot(Ab[n*NV + lane] > 0.f);
      const int mm = 64 + lane;
      unsigned long long m1 = __ballot((mm < NV) && (Ab[n*NV + mm] > 0.f));
      if (lane == 0) { sAM[2*n] = m0; sAM[2*n+1] = m1; }
    }
  }
  // W1 B-fragments straight from global (L2-resident, zero-padded)
  f16x8 bW[4], bL[4];
  #pragma unroll
  for (int k = 0; k < 4; ++k)
    bW[k] = *(const f16x8*)&W1tg[(wave*16 + lr)*KP + k*32 + lh*8];
  if (wave < 2) {
    #pragma unroll
    for (int k = 0; k < 4; ++k)
      bL[k] = *(const f16x8*)&W1tg[(128 + lr)*KP + k*32 + lh*8];
  }
  __syncthreads();

  // --- GEMM1: feats = Xm @ W1cat ; wave w -> f-tile w ; waves 0,1 logits ---
  #pragma unroll
  for (int m = 0; m < 7; ++m) {
    f32x4 acc = {0.f,0.f,0.f,0.f};
    #pragma unroll
    for (int k = 0; k < 4; ++k) {
      f16x8 af = *(const f16x8*)&sXm[(m*16 + lr)*KP + k*32 + lh*8];
      acc = mfma16(af, bW[k], acc);
    }
    f16x4 v;
    #pragma unroll
    for (int r = 0; r < 4; ++r) v[r] = (f16)acc[r];
    *(f16x4*)&sFt[(wave*16 + lr)*KP + m*16 + lh*4] = v;   // sFt[f][m]
  }
  if (wave < 2) {   // logit tile split: wave0 m0..3, wave1 m4..6
    const int mlo = wave ? 4 : 0, mhi = wave ? 7 : 4;
    for (int m = mlo; m < mhi; ++m) {
      f32x4 acc = {0.f,0.f,0.f,0.f};
      #pragma unroll
      for (int k = 0; k < 4; ++k) {
        f16x8 af = *(const f16x8*)&sXm[(m*16 + lr)*KP + k*32 + lh*8];
        acc = mfma16(af, bL[k], acc);
      }
      const int mg0 = m*16 + lh*4;
      if (lr < 5)       *(f32x4*)&sES[lr*112 + mg0] = acc;
      else if (lr < 10) *(f32x4*)&sEN[(lr-5)*112 + mg0] = acc;
    }
  }
  __syncthreads();

  // softmax sweep geometry: lane owns row nrow; waves split m-axis 4-ways
  const int half = wave & 1, q = wave >> 1;
  const int nrow = half*64 + lane;            // may be >= NV (inactive)
  const int m0base = q*32;
  const int nchunk = (q == 3) ? 2 : 4;        // q ranges: 32,32,32,16

  // --- 5 layer-1 head passes ---
  const int nt = wave & 1, mh = wave >> 1;
  f16 h1r[5][2][4];
  #pragma unroll
  for (int p = 0; p < 5; ++p) {
    if (nrow < NV) {
      const float es = sES[p*112 + nrow];
      const unsigned long long am = sAM[2*nrow + (q>>1)];
      float psum = 0.f;
      for (int c = 0; c < nchunk; ++c) {
        const int m0 = m0base + c*8;
        const f32x4 enA = *(const f32x4*)&sEN[p*112 + m0];
        const f32x4 enB = *(const f32x4*)&sEN[p*112 + m0 + 4];
        const unsigned bits = (unsigned)(am >> (m0 & 63)) & 0xFFu;
        f16x8 pk;
        #pragma unroll
        for (int j = 0; j < 8; ++j) {
          float v = es + ((j < 4) ? enA[j] : enB[j-4]);
          v = fmaxf(v, LALPHA*v);                 // leaky_relu
          v = ((bits >> j) & 1u) ? v : -1e30f;    // adjacency mask
          const float e = expm4(v);               // exp(v-4), fma+hw exp2
          psum += e;
          pk[j] = (f16)e;
        }
        *(f16x8*)&sXm[nrow*KP + m0] = pk;
      }
      sCMB[0][nrow][q] = psum;
    }
    __syncthreads();
    // GEMM2: h_p = Pnorm @ feats_p ; normalization folded into epilogue
    f16x8 bf[4];
    #pragma unroll
    for (int k = 0; k < 4; ++k)
      bf[k] = *(const f16x8*)&sFt[(p*NF1 + nt*16 + lr)*KP + k*32 + lh*8];
    const int fl = nt*16 + lr;
    const float bv = (fl < NF1) ? b1[fl] : 0.f;
    #pragma unroll
    for (int mi = 0; mi < 2; ++mi) {
      const int m = 2*mh + mi;
      if (m < 7) {
        f32x4 acc = {0.f,0.f,0.f,0.f};
        #pragma unroll
        for (int k = 0; k < 4; ++k) {
          f16x8 af = *(const f16x8*)&sXm[(m*16 + lr)*KP + k*32 + lh*8];
          acc = mfma16(af, bf[k], acc);
        }
        const int mg0 = m*16 + lh*4;
        #pragma unroll
        for (int r = 0; r < 4; ++r) {
          const f32x4 cm = *(const f32x4*)&sCMB[0][mg0 + r][0];
          const float inv = frcp(cm[0]+cm[1]+cm[2]+cm[3]);
          h1r[p][mi][r] = (f16)lrelu(acc[r]*inv + bv);
        }
      }
    }
    __syncthreads();
  }

  // --- dump h1 regs -> sXm[n][c] ---
  {
    const int fl = nt*16 + lr;
    if (fl < NF1) {
      #pragma unroll
      for (int p = 0; p < 5; ++p) {
        #pragma unroll
        for (int mi = 0; mi < 2; ++mi) {
          const int m = 2*mh + mi;
          if (m < 7) {
            #pragma unroll
            for (int r = 0; r < 4; ++r) {
              const int mg = m*16 + lh*4 + r;
              if (mg < NV) sXm[mg*KP + p*NF1 + fl] = h1r[p][mi][r];
            }
          }
        }
      }
    }
  }
  __syncthreads();

  // --- feats2 = h1 @ W2aug : cols 0..8 feats2, cols 9..14 logits ---
  if (wave < 7) {
    f16x8 bW2[4];
    #pragma unroll
    for (int k = 0; k < 4; ++k)
      bW2[k] = *(const f16x8*)&W2tg[lr*KP + k*32 + lh*8];
    f32x4 acc = {0.f,0.f,0.f,0.f};
    #pragma unroll
    for (int k = 0; k < 4; ++k) {
      f16x8 af = *(const f16x8*)&sXm[(wave*16 + lr)*KP + k*32 + lh*8];
      acc = mfma16(af, bW2[k], acc);
    }
    const int mg0 = wave*16 + lh*4;
    if (lr < 9) {
      #pragma unroll
      for (int r = 0; r < 4; ++r) {
        const int mg = mg0 + r;
        if (mg < NV) sF2t[lr*KP + mg] = (f16)acc[r];
      }
    } else if (lr < 12) {
      *(f32x4*)&sES[(lr-9)*112 + mg0] = acc;
    } else if (lr < 15) {
      *(f32x4*)&sEN[(lr-12)*112 + mg0] = acc;
    }
  }
  __syncthreads();

  // --- layer-2: pipelined sweep/GEMM3 with alternating P2 buffers ---
  auto sweep2 = [&](const float* __restrict__ esr, const float* __restrict__ enr,
                    float* __restrict__ cmb, f16* __restrict__ dst) {
    if (nrow < NV) {
      const float es = esr[nrow];
      const unsigned long long am = sAM[2*nrow + (q>>1)];
      float psum = 0.f;
      for (int c = 0; c < nchunk; ++c) {
        const int m0 = m0base + c*8;
        const f32x4 enA = *(const f32x4*)&enr[m0];
        const f32x4 enB = *(const f32x4*)&enr[m0 + 4];
        const unsigned bits = (unsigned)(am >> (m0 & 63)) & 0xFFu;
        f16x8 pk;
        #pragma unroll
        for (int j = 0; j < 8; ++j) {
          float v = es + ((j < 4) ? enA[j] : enB[j-4]);
          v = fmaxf(v, LALPHA*v);
          v = ((bits >> j) & 1u) ? v : -1e30f;
          const float e = expm4(v);
          psum += e;
          pk[j] = (f16)e;
        }
        *(f16x8*)&dst[nrow*KP + m0] = pk;
      }
      cmb[nrow*4 + q] = psum;
    }
  };
  auto gemm3 = [&](const f16* __restrict__ Pb, int g, f32x4& acc) {
    if (wave < 7) {
      const int brow = (lr < NF2) ? (g*NF2 + lr) : 15;   // row 15 stays zero
      f16x8 bf2[4];
      #pragma unroll
      for (int k = 0; k < 4; ++k)
        bf2[k] = *(const f16x8*)&sF2t[brow*KP + k*32 + lh*8];
      #pragma unroll
      for (int k = 0; k < 4; ++k) {
        f16x8 af = *(const f16x8*)&Pb[(wave*16 + lr)*KP + k*32 + lh*8];
        acc = mfma16(af, bf2[k], acc);
      }
    }
  };

  f32x4 acc2_0 = {0.f,0.f,0.f,0.f};
  f32x4 acc2_1 = {0.f,0.f,0.f,0.f};
  f32x4 acc2_2 = {0.f,0.f,0.f,0.f};
  sweep2(&sES[0],   &sEN[0],   &sCMB[0][0][0], sXm);
  __syncthreads();
  gemm3(sXm, 0, acc2_0);
  sweep2(&sES[112], &sEN[112], &sCMB[1][0][0], sFt);
  __syncthreads();
  gemm3(sFt, 1, acc2_1);
  sweep2(&sES[224], &sEN[224], &sCMB[2][0][0], sXm);
  __syncthreads();
  gemm3(sXm, 2, acc2_2);
  __syncthreads();

  // --- t[n] = sigmoid( lrelu(mean_g(acc2_g/sum_g) + b2) . fc1 ) ---
  if (wave < 7) {
    const int mg0 = wave*16 + lh*4;
    const float fcv = (lr < NF2) ? fc1w[lr] : 0.f;
    const float b2v = (lr < NF2) ? b2[lr]  : 0.f;
    #pragma unroll
    for (int r = 0; r < 4; ++r) {
      const int mg = mg0 + r;
      const f32x4 cm0 = *(const f32x4*)&sCMB[0][mg][0];
      const f32x4 cm1 = *(const f32x4*)&sCMB[1][mg][0];
      const f32x4 cm2 = *(const f32x4*)&sCMB[2][mg][0];
      const float hsum = acc2_0[r]*frcp(cm0[0]+cm0[1]+cm0[2]+cm0[3])
                       + acc2_1[r]*frcp(cm1[0]+cm1[1]+cm1[2]+cm1[3])
                       + acc2_2[r]*frcp(cm2[0]+cm2[1]+cm2[2]+cm2[3]);
      float hv = (lr < NF2) ? lrelu(hsum*(1.f/NH2) + b2v)*fcv : 0.f;
      hv += __shfl_xor(hv, 1);
      hv += __shfl_xor(hv, 2);
      hv += __shfl_xor(hv, 4);
      hv += __shfl_xor(hv, 8);
      if (lr == 0 && mg < NV) sT[mg] = sigm(hv);
    }
  }
  __syncthreads();
  // --- stage t16: t replicated across 16 rows (A-operand), zero-padded ---
  for (int i = tid; i < 16*KP; i += T1) {
    const int k = i % KP;
    t16[i] = (k < NV) ? (f16)sT[k] : (f16)0.f;
  }
  __syncthreads();
  // --- s = t @ fc2 via MFMA (fc2^T f16 from global) ---
  if (wave < 7) {
    f32x4 acc = {0.f,0.f,0.f,0.f};
    #pragma unroll
    for (int k = 0; k < 4; ++k) {
      f16x8 af = *(const f16x8*)&t16[lr*KP + k*32 + lh*8];
      f16x8 bf = *(const f16x8*)&fc2tg[(wave*16 + lr)*KP + k*32 + lh*8];
      acc = mfma16(af, bf, acc);
    }
    const int col = wave*16 + lr;
    if (lh == 0 && col < NV) sS[col] = acc[0];
  }
  __syncthreads();
  // --- out[b] = sum_m t[m]*softmax(s)[m] ---
  if (wave == 0) {
    const float s0 = sS[lane];
    const float s1 = (64+lane < NV) ? sS[64+lane] : -1e38f;
    const float mx = wmax(fmaxf(s0, s1));
    const float p0 = __expf(s0 - mx);
    const float p1 = (64+lane < NV) ? __expf(s1 - mx) : 0.f;
    const float sum = wsum(p0 + p1);
    float val = sT[lane]*p0 + ((64+lane < NV) ? sT[64+lane]*p1 : 0.f);
    val = wsum(val);
    if (lane == 0) out[b] = val*frcp(sum);
  }
}

extern "C" void kernel_launch(void* const* d_in, const int* in_sizes, int n_in,
                              void* d_out, int out_size, void* d_ws, size_t ws_size,
                              hipStream_t stream) {
  const float* X   = (const float*)d_in[0];
  const float* A   = (const float*)d_in[1];
  const float* M   = (const float*)d_in[2];
  const float* W1  = (const float*)d_in[3];
  const float* as1 = (const float*)d_in[4];
  const float* an1 = (const float*)d_in[5];
  const float* b1  = (const float*)d_in[6];
  const float* W2  = (const float*)d_in[7];
  const float* as2 = (const float*)d_in[8];
  const float* an2 = (const float*)d_in[9];
  const float* b2  = (const float*)d_in[10];
  const float* fc1 = (const float*)d_in[11];
  const float* fc2 = (const float*)d_in[12];
  float* out = (float*)d_out;

  // ws: Msig f32[12100] | W1tg f16[144*136] | W2tg f16[16*136] | fc2tg f16[112*136]
  float* Msig = (float*)d_ws;
  f16* W1tg  = (f16*)((char*)d_ws + 48400);
  f16* W2tg  = (f16*)((char*)d_ws + 48400 + W1ROWS*KP*2);
  f16* fc2tg = (f16*)((char*)d_ws + 48400 + W1ROWS*KP*2 + 16*KP*2);

  const int pre_items = NN + W1ROWS*KP + 16*KP + 112*KP;
  precomp_kernel<<<(pre_items + 255)/256, 256, 0, stream>>>(
      M, W1, as1, an1, W2, as2, an2, fc2, Msig, W1tg, W2tg, fc2tg);
  gat_fused<<<NB, T1, 0, stream>>>(X, A, Msig, W1tg, b1, W2tg,
                                   b2, fc1, fc2tg, out);
}

// Round 9
// 160.336 us; speedup vs baseline: 1.6815x; 1.1152x over previous
//
#include <hip/hip_runtime.h>
#include <math.h>

#define NB 2048
#define NV 110
#define NH1 5
#define NF1 24
#define NH2 3
#define NF2 3
#define C1 (NH1*NF1)   // 120
#define LALPHA 0.2f

constexpr int NN = NV*NV;          // 12100
constexpr int T1 = 512;
constexpr int KP = 136;            // padded K stride (halves)
constexpr int W1ROWS = 144;        // 120 feat cols + pad + 10 logit cols + pad

typedef _Float16 f16;
typedef f16  f16x8 __attribute__((ext_vector_type(8)));
typedef f16  f16x4 __attribute__((ext_vector_type(4)));
typedef float f32x4 __attribute__((ext_vector_type(4)));

__device__ __forceinline__ f32x4 mfma16(f16x8 a, f16x8 b, f32x4 c) {
  return __builtin_amdgcn_mfma_f32_16x16x32_f16(a, b, c, 0, 0, 0);
}
__device__ __forceinline__ float lrelu(float x){ return x > 0.f ? x : LALPHA*x; }
__device__ __forceinline__ float frcp(float x){ return __builtin_amdgcn_rcpf(x); }
__device__ __forceinline__ float sigm(float x){ return frcp(1.f+__expf(-x)); }
// exp(v-4) as a single fma + hw exp2
__device__ __forceinline__ float expm4(float v){
  return __builtin_amdgcn_exp2f(fmaf(v, 1.442695041f, -5.770780163f));
}
__device__ __forceinline__ float wmax(float v){
  #pragma unroll
  for (int d=32; d; d>>=1) v = fmaxf(v, __shfl_xor(v,d));
  return v;
}
__device__ __forceinline__ float wsum(float v){
  #pragma unroll
  for (int d=32; d; d>>=1) v += __shfl_xor(v,d);
  return v;
}
__device__ __forceinline__ f32x4 ld4u(const float* p){
  f32x4 v; __builtin_memcpy(&v, p, 16); return v;
}

// ---- Kernel 0: precompute sigmoid(M), augmented W1^T, augmented W2^T, fc2^T ----
// W1tg rows: 0..119 = W1^T cat; 128+h = es-col head h; 133+h = en-col; rest 0
// W2tg rows: 0..8 = W2^T cat; 9+g = es2-col; 12+g = en2-col; 15 = 0
// fc2tg rows j=0..111: fc2tg[j][k] = fc2[k][j] (f16, zero-padded)
__global__ void precomp_kernel(const float* __restrict__ M, const float* __restrict__ W1,
                               const float* __restrict__ as1, const float* __restrict__ an1,
                               const float* __restrict__ W2, const float* __restrict__ as2,
                               const float* __restrict__ an2, const float* __restrict__ fc2w,
                               float* __restrict__ Msig, f16* __restrict__ W1tg,
                               f16* __restrict__ W2tg, f16* __restrict__ fc2tg) {
  const int i = blockIdx.x*256 + threadIdx.x;
  if (i < NN) {
    Msig[i] = sigm(M[i]);
  } else if (i < NN + W1ROWS*KP) {
    const int j = i - NN, f = j/KP, k = j%KP;
    float v = 0.f;
    if (k < NV) {
      if (f < C1) {
        v = W1[(f/NF1)*(NV*NF1) + k*NF1 + (f%NF1)];
      } else if (f >= 128 && f < 133) {
        const int h = f - 128;
        for (int ff = 0; ff < NF1; ++ff)
          v += W1[h*(NV*NF1) + k*NF1 + ff] * as1[h*NF1 + ff];
      } else if (f >= 133 && f < 138) {
        const int h = f - 133;
        for (int ff = 0; ff < NF1; ++ff)
          v += W1[h*(NV*NF1) + k*NF1 + ff] * an1[h*NF1 + ff];
      }
    }
    W1tg[f*KP + k] = (f16)v;
  } else if (i < NN + W1ROWS*KP + 16*KP) {
    const int j = i - NN - W1ROWS*KP, r = j/KP, k = j%KP;
    float v = 0.f;
    if (k < C1) {
      if (r < 9) {
        v = W2[(r/NF2)*(C1*NF2) + k*NF2 + (r%NF2)];
      } else if (r < 12) {
        const int g = r - 9;
        for (int f2 = 0; f2 < NF2; ++f2)
          v += W2[g*(C1*NF2) + k*NF2 + f2] * as2[g*NF2 + f2];
      } else if (r < 15) {
        const int g = r - 12;
        for (int f2 = 0; f2 < NF2; ++f2)
          v += W2[g*(C1*NF2) + k*NF2 + f2] * an2[g*NF2 + f2];
      }
    }
    W2tg[r*KP + k] = (f16)v;
  } else if (i < NN + W1ROWS*KP + 16*KP + 112*KP) {
    const int j = i - NN - W1ROWS*KP - 16*KP, col = j/KP, k = j%KP;
    float v = 0.f;
    if (col < NV && k < NV) v = fc2w[k*NV + col];
    fc2tg[col*KP + k] = (f16)v;
  }
}

// ---- fully fused GAT: layer1 + layer2 + readout, one block per batch ----
__global__ __launch_bounds__(T1, 4) void gat_fused(
  const float* __restrict__ X, const float* __restrict__ A,
  const float* __restrict__ Msig, const f16* __restrict__ W1tg,
  const float* __restrict__ b1,  const f16* __restrict__ W2tg,
  const float* __restrict__ b2,  const float* __restrict__ fc1w,
  const f16* __restrict__ fc2tg, float* __restrict__ out)
{
  // LDS = 30464+34816+4352+2240+2560+1344+1536+1792+448+1344 = 80,896 B (2 blocks/CU)
  __shared__ __attribute__((aligned(16))) f16 sXm [112*KP]; // Xm, then h1[n][c]
  __shared__ __attribute__((aligned(16))) f16 sFt [128*KP]; // feats^T [f][m]
  __shared__ __attribute__((aligned(16))) f16 sF2t[16*KP];  // feats2^T / t16
  __shared__ __attribute__((aligned(16))) float sES [NH1*112]; // L1 es / sT,sS alias
  __shared__ __attribute__((aligned(16))) float sEN [NH1*128]; // L1 en
  __shared__ __attribute__((aligned(16))) float sES2[NH2*112]; // L2 es
  __shared__ __attribute__((aligned(16))) float sEN2[NH2*128]; // L2 en
  __shared__ unsigned long long sAM[2*112];
  __shared__ __attribute__((aligned(16))) float sROW [112];    // L1 row expsum
  __shared__ __attribute__((aligned(16))) float sROW2[3*112];  // L2 row expsum

  const int b = blockIdx.x, tid = threadIdx.x;
  const int wv = tid >> 6, lane = tid & 63;
  const int lr = lane & 15, lh = lane >> 4;
  const float* __restrict__ Xb = X + (size_t)b*NN;
  const float* __restrict__ Ab = A + (size_t)b*NN;

  float* const sT = sES;          // aliases, used only in the final phase
  float* const sS = sES + 112;
  f16*   const t16 = sF2t;        // alias: t replicated rows (readout MFMA)

  // --- pad-only zero-init (disjoint from staged regions) ---
  for (int n = tid; n < 110; n += T1) {       // sXm rows<110: cols 110..135
    *(unsigned*)&sXm[n*KP + 110] = 0u;
    *(uint4*)&sXm[n*KP + 112] = uint4{0,0,0,0};
    *(uint4*)&sXm[n*KP + 120] = uint4{0,0,0,0};
    *(uint4*)&sXm[n*KP + 128] = uint4{0,0,0,0};
  }
  for (int i = tid; i < 2*KP/8; i += T1)      // sXm rows 110,111 full
    ((uint4*)&sXm[110*KP])[i] = uint4{0,0,0,0};
  for (int n = tid; n < 128; n += T1) {       // sFt: cols 112..135 per row
    *(uint4*)&sFt[n*KP + 112] = uint4{0,0,0,0};
    *(uint4*)&sFt[n*KP + 120] = uint4{0,0,0,0};
    *(uint4*)&sFt[n*KP + 128] = uint4{0,0,0,0};
  }
  for (int i = tid; i < (16*KP)/8; i += T1)   // sF2t entirely
    ((uint4*)sF2t)[i] = uint4{0,0,0,0};
  if (tid < 4) sAM[220 + tid] = 0ull;         // mask pad rows 110,111

  // --- stage Xm = X * Msig (float4 loads), adjacency ballot ---
  for (int t = tid; t < NV*28; t += T1) {
    const int n = t/28, c = t%28, k = 4*c;
    if (c < 27) {
      f32x4 x = ld4u(Xb + n*NV + k);
      f32x4 m = ld4u(Msig + n*NV + k);
      f16x4 v;
      #pragma unroll
      for (int j = 0; j < 4; ++j) v[j] = (f16)(x[j]*m[j]);
      *(f16x4*)&sXm[n*KP + k] = v;
    } else {
      sXm[n*KP + 108] = (f16)(Xb[n*NV+108]*Msig[n*NV+108]);
      sXm[n*KP + 109] = (f16)(Xb[n*NV+109]*Msig[n*NV+109]);
    }
  }
  #pragma unroll
  for (int i = 0; i < 14; ++i) {
    const int n = wv + 8*i;                       // wave-uniform
    if (n < NV) {
      unsigned long long m0 = __ballot(Ab[n*NV + lane] > 0.f);
      const int mm = 64 + lane;
      unsigned long long m1 = __ballot((mm < NV) && (Ab[n*NV + mm] > 0.f));
      if (lane == 0) { sAM[2*n] = m0; sAM[2*n+1] = m1; }
    }
  }
  // W1 B-fragments straight from global (L2-resident, zero-padded)
  f16x8 bW[4], bL[4];
  #pragma unroll
  for (int k = 0; k < 4; ++k)
    bW[k] = *(const f16x8*)&W1tg[(wv*16 + lr)*KP + k*32 + lh*8];
  if (wv < 2) {
    #pragma unroll
    for (int k = 0; k < 4; ++k)
      bL[k] = *(const f16x8*)&W1tg[(128 + lr)*KP + k*32 + lh*8];
  }
  __syncthreads();   // (1) Xm/masks staged

  // --- GEMM1: feats = Xm @ W1cat ; wave w -> f-tile w ; waves 0,1 logits ---
  #pragma unroll
  for (int m = 0; m < 7; ++m) {
    f32x4 acc = {0.f,0.f,0.f,0.f};
    #pragma unroll
    for (int k = 0; k < 4; ++k) {
      f16x8 af = *(const f16x8*)&sXm[(m*16 + lr)*KP + k*32 + lh*8];
      acc = mfma16(af, bW[k], acc);
    }
    f16x4 v;
    #pragma unroll
    for (int r = 0; r < 4; ++r) v[r] = (f16)acc[r];
    *(f16x4*)&sFt[(wv*16 + lr)*KP + m*16 + lh*4] = v;   // sFt[f][m]
  }
  if (wv < 2) {   // logit tile split: wave0 m0..3, wave1 m4..6
    const int mlo = wv ? 4 : 0, mhi = wv ? 7 : 4;
    for (int m = mlo; m < mhi; ++m) {
      f32x4 acc = {0.f,0.f,0.f,0.f};
      #pragma unroll
      for (int k = 0; k < 4; ++k) {
        f16x8 af = *(const f16x8*)&sXm[(m*16 + lr)*KP + k*32 + lh*8];
        acc = mfma16(af, bL[k], acc);
      }
      const int mg0 = m*16 + lh*4;
      if (lr < 5)       *(f32x4*)&sES[lr*112 + mg0] = acc;
      else if (lr < 10) *(f32x4*)&sEN[(lr-5)*128 + mg0] = acc;
    }
  }
  __syncthreads();   // (2) feats^T + L1 logits visible

  // ============ L1 passes: wave w owns m-tile w; P lives in registers ======
  const int row  = wv*16 + lr;
  const int arow = (row < 112) ? row : 0;     // clamp (wave 7 rows unused)
  const unsigned long long am0 = sAM[2*arow], am1 = sAM[2*arow+1];
  const float bvt0 = (lr < NF1) ? b1[lr] : 0.f;
  const float bvt1 = (16 + lr < NF1) ? b1[16 + lr] : 0.f;

  f16 h1r[5][2][4];
  f16x8 pa[4];
  #pragma unroll
  for (int p = 0; p < 5; ++p) {
    if (wv < 7) {
      const float es = sES[p*112 + row];
      float psum = 0.f;
      #pragma unroll
      for (int k = 0; k < 4; ++k) {
        const int cb = k*32 + lh*8;
        const f32x4 enA = *(const f32x4*)&sEN[p*128 + cb];
        const f32x4 enB = *(const f32x4*)&sEN[p*128 + cb + 4];
        const unsigned bits = (unsigned)(((cb & 64) ? am1 : am0) >> (cb & 63)) & 0xFFu;
        f16x8 pk;
        #pragma unroll
        for (int j = 0; j < 8; ++j) {
          float v = es + ((j < 4) ? enA[j] : enB[j-4]);
          v = fmaxf(v, LALPHA*v);                 // leaky_relu
          v = (bits & (1u << j)) ? v : -1e30f;    // adjacency mask
          const float e = expm4(v);               // exp(v-4)
          psum += e;
          pk[j] = (f16)e;
        }
        pa[k] = pk;
      }
      psum += __shfl_xor(psum, 16);     // row-sum across lh groups
      psum += __shfl_xor(psum, 32);
      if (lh == 0) sROW[row] = psum;
    }
    __syncthreads();                    // P row-sums visible
    if (wv < 7) {
      // GEMM2 (both f-tiles) with self-computed A-fragments
      #pragma unroll
      for (int nt2 = 0; nt2 < 2; ++nt2) {
        f32x4 acc = {0.f,0.f,0.f,0.f};
        #pragma unroll
        for (int k = 0; k < 4; ++k) {
          f16x8 bf = *(const f16x8*)&sFt[(p*NF1 + nt2*16 + lr)*KP + k*32 + lh*8];
          acc = mfma16(pa[k], bf, acc);
        }
        const f32x4 rs = *(const f32x4*)&sROW[wv*16 + lh*4];
        const float bv = nt2 ? bvt1 : bvt0;
        #pragma unroll
        for (int r = 0; r < 4; ++r)
          h1r[p][nt2][r] = (f16)lrelu(acc[r]*frcp(rs[r]) + bv);
      }
    }
  }

  // --- dump h1 regs -> sXm rows of own m-tile ---
  if (wv < 7) {
    #pragma unroll
    for (int p = 0; p < 5; ++p) {
      #pragma unroll
      for (int nt2 = 0; nt2 < 2; ++nt2) {
        const int fl = nt2*16 + lr;
        if (fl < NF1) {
          #pragma unroll
          for (int r = 0; r < 4; ++r) {
            const int mg = wv*16 + lh*4 + r;
            if (mg < NV) sXm[mg*KP + p*NF1 + fl] = h1r[p][nt2][r];
          }
        }
      }
    }
  }
  __syncthreads();   // (3a) h1 complete

  // --- feats2 = h1 @ W2aug : cols 0..8 feats2, cols 9..14 logits ---
  if (wv < 7) {
    f32x4 acc = {0.f,0.f,0.f,0.f};
    #pragma unroll
    for (int k = 0; k < 4; ++k) {
      f16x8 af = *(const f16x8*)&sXm[(wv*16 + lr)*KP + k*32 + lh*8];
      f16x8 bf = *(const f16x8*)&W2tg[lr*KP + k*32 + lh*8];
      acc = mfma16(af, bf, acc);
    }
    const int mg0 = wv*16 + lh*4;
    if (lr < 9) {
      #pragma unroll
      for (int r = 0; r < 4; ++r) {
        const int mg = mg0 + r;
        if (mg < NV) sF2t[lr*KP + mg] = (f16)acc[r];
      }
    } else if (lr < 12) {
      *(f32x4*)&sES2[(lr-9)*112 + mg0] = acc;
    } else if (lr < 15) {
      *(f32x4*)&sEN2[(lr-12)*128 + mg0] = acc;
    }
  }
  __syncthreads();   // (3b) feats2^T + L2 logits visible

  // ============ L2 passes: P2 in registers, per-head accumulators ==========
  f32x4 a2_0 = {0.f,0.f,0.f,0.f};
  f32x4 a2_1 = {0.f,0.f,0.f,0.f};
  f32x4 a2_2 = {0.f,0.f,0.f,0.f};
  if (wv < 7) {
    #pragma unroll
    for (int g = 0; g < 3; ++g) {
      const float es = sES2[g*112 + row];
      float psum = 0.f;
      #pragma unroll
      for (int k = 0; k < 4; ++k) {
        const int cb = k*32 + lh*8;
        const f32x4 enA = *(const f32x4*)&sEN2[g*128 + cb];
        const f32x4 enB = *(const f32x4*)&sEN2[g*128 + cb + 4];
        const unsigned bits = (unsigned)(((cb & 64) ? am1 : am0) >> (cb & 63)) & 0xFFu;
        f16x8 pk;
        #pragma unroll
        for (int j = 0; j < 8; ++j) {
          float v = es + ((j < 4) ? enA[j] : enB[j-4]);
          v = fmaxf(v, LALPHA*v);
          v = (bits & (1u << j)) ? v : -1e30f;
          const float e = expm4(v);
          psum += e;
          pk[j] = (f16)e;
        }
        pa[k] = pk;
      }
      psum += __shfl_xor(psum, 16);
      psum += __shfl_xor(psum, 32);
      if (lh == 0) sROW2[g*112 + row] = psum;
      const int brow = (lr < NF2) ? (g*NF2 + lr) : 15;   // row 15 stays zero
      #pragma unroll
      for (int k = 0; k < 4; ++k) {
        f16x8 bf = *(const f16x8*)&sF2t[brow*KP + k*32 + lh*8];
        if (g == 0)      a2_0 = mfma16(pa[k], bf, a2_0);
        else if (g == 1) a2_1 = mfma16(pa[k], bf, a2_1);
        else             a2_2 = mfma16(pa[k], bf, a2_2);
      }
    }
  }
  __syncthreads();   // L2 row-sums visible

  // --- t[n] = sigmoid( lrelu(mean_g(a2_g/sum_g) + b2) . fc1 ) ---
  if (wv < 7) {
    const int mg0 = wv*16 + lh*4;
    const float fcv = (lr < NF2) ? fc1w[lr] : 0.f;
    const float b2v = (lr < NF2) ? b2[lr]  : 0.f;
    const f32x4 rs0 = *(const f32x4*)&sROW2[0*112 + mg0];
    const f32x4 rs1 = *(const f32x4*)&sROW2[1*112 + mg0];
    const f32x4 rs2 = *(const f32x4*)&sROW2[2*112 + mg0];
    #pragma unroll
    for (int r = 0; r < 4; ++r) {
      const float hsum = a2_0[r]*frcp(rs0[r]) + a2_1[r]*frcp(rs1[r])
                       + a2_2[r]*frcp(rs2[r]);
      float hv = (lr < NF2) ? lrelu(hsum*(1.f/NH2) + b2v)*fcv : 0.f;
      hv += __shfl_xor(hv, 1);
      hv += __shfl_xor(hv, 2);
      hv += __shfl_xor(hv, 4);
      hv += __shfl_xor(hv, 8);
      if (lr == 0) {
        const int mg = mg0 + r;
        if (mg < NV) sT[mg] = sigm(hv);
      }
    }
  }
  __syncthreads();   // (4) sT complete; sF2t reads done
  // --- stage t16: t replicated across 16 rows (A-operand), zero-padded ---
  for (int i = tid; i < 16*KP; i += T1) {
    const int k = i % KP;
    t16[i] = (k < NV) ? (f16)sT[k] : (f16)0.f;
  }
  __syncthreads();   // (5)
  // --- s = t @ fc2 via MFMA (fc2^T f16 from global) ---
  if (wv < 7) {
    f32x4 acc = {0.f,0.f,0.f,0.f};
    #pragma unroll
    for (int k = 0; k < 4; ++k) {
      f16x8 af = *(const f16x8*)&t16[lr*KP + k*32 + lh*8];
      f16x8 bf = *(const f16x8*)&fc2tg[(wv*16 + lr)*KP + k*32 + lh*8];
      acc = mfma16(af, bf, acc);
    }
    const int col = wv*16 + lr;
    if (lh == 0 && col < NV) sS[col] = acc[0];
  }
  __syncthreads();   // (6)
  // --- out[b] = sum_m t[m]*softmax(s)[m] ---
  if (wv == 0) {
    const float s0 = sS[lane];
    const float s1 = (64+lane < NV) ? sS[64+lane] : -1e38f;
    const float mx = wmax(fmaxf(s0, s1));
    const float p0 = __expf(s0 - mx);
    const float p1 = (64+lane < NV) ? __expf(s1 - mx) : 0.f;
    const float sum = wsum(p0 + p1);
    float val = sT[lane]*p0 + ((64+lane < NV) ? sT[64+lane]*p1 : 0.f);
    val = wsum(val);
    if (lane == 0) out[b] = val*frcp(sum);
  }
}

extern "C" void kernel_launch(void* const* d_in, const int* in_sizes, int n_in,
                              void* d_out, int out_size, void* d_ws, size_t ws_size,
                              hipStream_t stream) {
  const float* X   = (const float*)d_in[0];
  const float* A   = (const float*)d_in[1];
  const float* M   = (const float*)d_in[2];
  const float* W1  = (const float*)d_in[3];
  const float* as1 = (const float*)d_in[4];
  const float* an1 = (const float*)d_in[5];
  const float* b1  = (const float*)d_in[6];
  const float* W2  = (const float*)d_in[7];
  const float* as2 = (const float*)d_in[8];
  const float* an2 = (const float*)d_in[9];
  const float* b2  = (const float*)d_in[10];
  const float* fc1 = (const float*)d_in[11];
  const float* fc2 = (const float*)d_in[12];
  float* out = (float*)d_out;

  // ws: Msig f32[12100] | W1tg f16[144*136] | W2tg f16[16*136] | fc2tg f16[112*136]
  float* Msig = (float*)d_ws;
  f16* W1tg  = (f16*)((char*)d_ws + 48400);
  f16* W2tg  = (f16*)((char*)d_ws + 48400 + W1ROWS*KP*2);
  f16* fc2tg = (f16*)((char*)d_ws + 48400 + W1ROWS*KP*2 + 16*KP*2);

  const int pre_items = NN + W1ROWS*KP + 16*KP + 112*KP;
  precomp_kernel<<<(pre_items + 255)/256, 256, 0, stream>>>(
      M, W1, as1, an1, W2, as2, an2, fc2, Msig, W1tg, W2tg, fc2tg);
  gat_fused<<<NB, T1, 0, stream>>>(X, A, Msig, W1tg, b1, W2tg,
                                   b2, fc1, fc2tg, out);
}

// Round 10
// 148.691 us; speedup vs baseline: 1.8132x; 1.0783x over previous
//
#include <hip/hip_runtime.h>
#include <math.h>

#define NB 2048
#define NV 110
#define NH1 5
#define NF1 24
#define NH2 3
#define NF2 3
#define C1 (NH1*NF1)   // 120
#define LALPHA 0.2f

constexpr int NN = NV*NV;          // 12100
constexpr int T1 = 512;
constexpr int KP = 136;            // padded K stride (halves)
constexpr int W1ROWS = 144;        // 120 feat cols + pad + 10 logit cols + pad

typedef _Float16 f16;
typedef f16  f16x8 __attribute__((ext_vector_type(8)));
typedef f16  f16x4 __attribute__((ext_vector_type(4)));
typedef __fp16 h16x2 __attribute__((ext_vector_type(2)));
typedef float f32x4 __attribute__((ext_vector_type(4)));

__device__ __forceinline__ f32x4 mfma16(f16x8 a, f16x8 b, f32x4 c) {
  return __builtin_amdgcn_mfma_f32_16x16x32_f16(a, b, c, 0, 0, 0);
}
__device__ __forceinline__ float lrelu(float x){ return x > 0.f ? x : LALPHA*x; }
__device__ __forceinline__ float frcp(float x){ return __builtin_amdgcn_rcpf(x); }
__device__ __forceinline__ float sigm(float x){ return frcp(1.f+__expf(-x)); }
// exp(v-4) as a single fma + hw exp2
__device__ __forceinline__ float expm4(float v){
  return __builtin_amdgcn_exp2f(fmaf(v, 1.442695041f, -5.770780163f));
}
__device__ __forceinline__ float wmax(float v){
  #pragma unroll
  for (int d=32; d; d>>=1) v = fmaxf(v, __shfl_xor(v,d));
  return v;
}
__device__ __forceinline__ float wsum(float v){
  #pragma unroll
  for (int d=32; d; d>>=1) v += __shfl_xor(v,d);
  return v;
}
__device__ __forceinline__ f32x4 ld4u(const float* p){
  f32x4 v; __builtin_memcpy(&v, p, 16); return v;
}

// ---- Kernel 0: precompute sigmoid(M), augmented W1^T, augmented W2^T, fc2^T ----
// W1tg rows: 0..119 = W1^T cat; 128+h = es-col head h; 133+h = en-col; rest 0
// W2tg rows: 0..8 = W2^T cat; 9+g = es2-col; 12+g = en2-col; 15 = 0
// fc2tg rows j=0..111: fc2tg[j][k] = fc2[k][j] (f16, zero-padded)
__global__ void precomp_kernel(const float* __restrict__ M, const float* __restrict__ W1,
                               const float* __restrict__ as1, const float* __restrict__ an1,
                               const float* __restrict__ W2, const float* __restrict__ as2,
                               const float* __restrict__ an2, const float* __restrict__ fc2w,
                               float* __restrict__ Msig, f16* __restrict__ W1tg,
                               f16* __restrict__ W2tg, f16* __restrict__ fc2tg) {
  const int i = blockIdx.x*256 + threadIdx.x;
  if (i < NN) {
    Msig[i] = sigm(M[i]);
  } else if (i < NN + W1ROWS*KP) {
    const int j = i - NN, f = j/KP, k = j%KP;
    float v = 0.f;
    if (k < NV) {
      if (f < C1) {
        v = W1[(f/NF1)*(NV*NF1) + k*NF1 + (f%NF1)];
      } else if (f >= 128 && f < 133) {
        const int h = f - 128;
        for (int ff = 0; ff < NF1; ++ff)
          v += W1[h*(NV*NF1) + k*NF1 + ff] * as1[h*NF1 + ff];
      } else if (f >= 133 && f < 138) {
        const int h = f - 133;
        for (int ff = 0; ff < NF1; ++ff)
          v += W1[h*(NV*NF1) + k*NF1 + ff] * an1[h*NF1 + ff];
      }
    }
    W1tg[f*KP + k] = (f16)v;
  } else if (i < NN + W1ROWS*KP + 16*KP) {
    const int j = i - NN - W1ROWS*KP, r = j/KP, k = j%KP;
    float v = 0.f;
    if (k < C1) {
      if (r < 9) {
        v = W2[(r/NF2)*(C1*NF2) + k*NF2 + (r%NF2)];
      } else if (r < 12) {
        const int g = r - 9;
        for (int f2 = 0; f2 < NF2; ++f2)
          v += W2[g*(C1*NF2) + k*NF2 + f2] * as2[g*NF2 + f2];
      } else if (r < 15) {
        const int g = r - 12;
        for (int f2 = 0; f2 < NF2; ++f2)
          v += W2[g*(C1*NF2) + k*NF2 + f2] * an2[g*NF2 + f2];
      }
    }
    W2tg[r*KP + k] = (f16)v;
  } else if (i < NN + W1ROWS*KP + 16*KP + 112*KP) {
    const int j = i - NN - W1ROWS*KP - 16*KP, col = j/KP, k = j%KP;
    float v = 0.f;
    if (col < NV && k < NV) v = fc2w[k*NV + col];
    fc2tg[col*KP + k] = (f16)v;
  }
}

// ---- fully fused GAT: layer1 + layer2 + readout, one block per batch ----
__global__ __launch_bounds__(T1, 4) void gat_fused(
  const float* __restrict__ X, const float* __restrict__ A,
  const float* __restrict__ Msig, const f16* __restrict__ W1tg,
  const float* __restrict__ b1,  const f16* __restrict__ W2tg,
  const float* __restrict__ b2,  const float* __restrict__ fc1w,
  const f16* __restrict__ fc2tg, float* __restrict__ out)
{
  // LDS = 80,896 B (2 blocks/CU)
  __shared__ __attribute__((aligned(16))) f16 sXm [112*KP]; // Xm, then h1[n][c]
  __shared__ __attribute__((aligned(16))) f16 sFt [128*KP]; // feats^T [f][m]
  __shared__ __attribute__((aligned(16))) f16 sF2t[16*KP];  // feats2^T / t16
  __shared__ __attribute__((aligned(16))) float sES [NH1*112]; // L1 es / sT,sS alias
  __shared__ __attribute__((aligned(16))) float sEN [NH1*128]; // L1 en
  __shared__ __attribute__((aligned(16))) float sES2[NH2*112]; // L2 es
  __shared__ __attribute__((aligned(16))) float sEN2[NH2*128]; // L2 en
  __shared__ unsigned long long sAM[2*112];
  __shared__ __attribute__((aligned(16))) float sROW [112];    // L1 row expsum
  __shared__ __attribute__((aligned(16))) float sROW2[3*112];  // L2 row expsum

  const int b = blockIdx.x, tid = threadIdx.x;
  const int wv = tid >> 6, lane = tid & 63;
  const int lr = lane & 15, lh = lane >> 4;
  const float* __restrict__ Xb = X + (size_t)b*NN;
  const float* __restrict__ Ab = A + (size_t)b*NN;

  float* const sT = sES;          // aliases, used only in the final phase
  float* const sS = sES + 112;
  f16*   const t16 = sF2t;        // alias: t replicated rows (readout MFMA)

  // --- pad-only zero-init (disjoint from staged regions) ---
  for (int n = tid; n < 110; n += T1) {       // sXm rows<110: cols 110..135
    *(unsigned*)&sXm[n*KP + 110] = 0u;
    *(uint4*)&sXm[n*KP + 112] = uint4{0,0,0,0};
    *(uint4*)&sXm[n*KP + 120] = uint4{0,0,0,0};
    *(uint4*)&sXm[n*KP + 128] = uint4{0,0,0,0};
  }
  for (int i = tid; i < 2*KP/8; i += T1)      // sXm rows 110,111 full
    ((uint4*)&sXm[110*KP])[i] = uint4{0,0,0,0};
  for (int n = tid; n < 128; n += T1) {       // sFt: cols 112..135 per row
    *(uint4*)&sFt[n*KP + 112] = uint4{0,0,0,0};
    *(uint4*)&sFt[n*KP + 120] = uint4{0,0,0,0};
    *(uint4*)&sFt[n*KP + 128] = uint4{0,0,0,0};
  }
  for (int i = tid; i < (16*KP)/8; i += T1)   // sF2t entirely
    ((uint4*)sF2t)[i] = uint4{0,0,0,0};
  if (tid < 4) sAM[220 + tid] = 0ull;         // mask pad rows 110,111

  // --- stage Xm = X * Msig (float4 loads, pkrtz pack), adjacency ballot ---
  for (int t = tid; t < NV*28; t += T1) {
    const int n = t/28, c = t%28, k = 4*c;
    if (c < 27) {
      f32x4 x = ld4u(Xb + n*NV + k);
      f32x4 m = ld4u(Msig + n*NV + k);
      union { f16x4 v4; h16x2 h2[2]; } u;
      u.h2[0] = __builtin_amdgcn_cvt_pkrtz(x[0]*m[0], x[1]*m[1]);
      u.h2[1] = __builtin_amdgcn_cvt_pkrtz(x[2]*m[2], x[3]*m[3]);
      *(f16x4*)&sXm[n*KP + k] = u.v4;
    } else {
      sXm[n*KP + 108] = (f16)(Xb[n*NV+108]*Msig[n*NV+108]);
      sXm[n*KP + 109] = (f16)(Xb[n*NV+109]*Msig[n*NV+109]);
    }
  }
  #pragma unroll
  for (int i = 0; i < 14; ++i) {
    const int n = wv + 8*i;                       // wave-uniform
    if (n < NV) {
      unsigned long long m0 = __ballot(Ab[n*NV + lane] > 0.f);
      const int mm = 64 + lane;
      unsigned long long m1 = __ballot((mm < NV) && (Ab[n*NV + mm] > 0.f));
      if (lane == 0) { sAM[2*n] = m0; sAM[2*n+1] = m1; }
    }
  }
  // W1 B-fragments straight from global (L2-resident, zero-padded)
  f16x8 bW[4], bL[4];
  #pragma unroll
  for (int k = 0; k < 4; ++k)
    bW[k] = *(const f16x8*)&W1tg[(wv*16 + lr)*KP + k*32 + lh*8];
  if (wv < 2) {
    #pragma unroll
    for (int k = 0; k < 4; ++k)
      bL[k] = *(const f16x8*)&W1tg[(128 + lr)*KP + k*32 + lh*8];
  }
  __syncthreads();   // (1) Xm/masks staged

  // --- GEMM1: feats = Xm @ W1cat ; wave w -> f-tile w ; waves 0,1 logits ---
  #pragma unroll
  for (int m = 0; m < 7; ++m) {
    f32x4 acc = {0.f,0.f,0.f,0.f};
    #pragma unroll
    for (int k = 0; k < 4; ++k) {
      f16x8 af = *(const f16x8*)&sXm[(m*16 + lr)*KP + k*32 + lh*8];
      acc = mfma16(af, bW[k], acc);
    }
    f16x4 v;
    #pragma unroll
    for (int r = 0; r < 4; ++r) v[r] = (f16)acc[r];
    *(f16x4*)&sFt[(wv*16 + lr)*KP + m*16 + lh*4] = v;   // sFt[f][m]
  }
  if (wv < 2) {   // logit tile split: wave0 m0..3, wave1 m4..6
    const int mlo = wv ? 4 : 0, mhi = wv ? 7 : 4;
    for (int m = mlo; m < mhi; ++m) {
      f32x4 acc = {0.f,0.f,0.f,0.f};
      #pragma unroll
      for (int k = 0; k < 4; ++k) {
        f16x8 af = *(const f16x8*)&sXm[(m*16 + lr)*KP + k*32 + lh*8];
        acc = mfma16(af, bL[k], acc);
      }
      const int mg0 = m*16 + lh*4;
      if (lr < 5)       *(f32x4*)&sES[lr*112 + mg0] = acc;
      else if (lr < 10) *(f32x4*)&sEN[(lr-5)*128 + mg0] = acc;
    }
  }
  __syncthreads();   // (2) feats^T + L1 logits visible

  // ============ L1 passes: wave w owns m-tile w; P in registers ============
  // All intra-pass handoffs are same-wave (sROW rows & h1 rows owned by the
  // wave that reads them) -> no barriers until the cross-wave feats2 handoff.
  const int row  = wv*16 + lr;
  const int arow = (row < 112) ? row : 0;     // clamp (wave 7 rows unused)
  const unsigned long long am0 = sAM[2*arow], am1 = sAM[2*arow+1];
  const float bvt0 = (lr < NF1) ? b1[lr] : 0.f;
  const float bvt1 = (16 + lr < NF1) ? b1[16 + lr] : 0.f;

  f16 h1r[5][2][4];
  f16x8 pa[4];
  if (wv < 7) {
    #pragma unroll
    for (int p = 0; p < 5; ++p) {
      const float es = sES[p*112 + row];
      float psum = 0.f;
      #pragma unroll
      for (int k = 0; k < 4; ++k) {
        const int cb = k*32 + lh*8;
        const f32x4 enA = *(const f32x4*)&sEN[p*128 + cb];
        const f32x4 enB = *(const f32x4*)&sEN[p*128 + cb + 4];
        const unsigned bits = (unsigned)(((cb & 64) ? am1 : am0) >> (cb & 63)) & 0xFFu;
        float e[8];
        #pragma unroll
        for (int j = 0; j < 8; ++j) {
          float v = es + ((j < 4) ? enA[j] : enB[j-4]);
          v = fmaxf(v, LALPHA*v);                 // leaky_relu
          v = (bits & (1u << j)) ? v : -1e30f;    // adjacency mask
          e[j] = expm4(v);                        // exp(v-4)
          psum += e[j];
        }
        union { f16x8 v8; h16x2 h2[4]; } u;
        u.h2[0] = __builtin_amdgcn_cvt_pkrtz(e[0], e[1]);
        u.h2[1] = __builtin_amdgcn_cvt_pkrtz(e[2], e[3]);
        u.h2[2] = __builtin_amdgcn_cvt_pkrtz(e[4], e[5]);
        u.h2[3] = __builtin_amdgcn_cvt_pkrtz(e[6], e[7]);
        pa[k] = u.v8;
      }
      psum += __shfl_xor(psum, 16);     // row-sum across lh groups
      psum += __shfl_xor(psum, 32);
      if (lh == 0) sROW[row] = psum;    // wave-private rows: same-wave handoff
      // GEMM2 (both f-tiles) with self-computed A-fragments
      #pragma unroll
      for (int nt2 = 0; nt2 < 2; ++nt2) {
        f32x4 acc = {0.f,0.f,0.f,0.f};
        #pragma unroll
        for (int k = 0; k < 4; ++k) {
          f16x8 bf = *(const f16x8*)&sFt[(p*NF1 + nt2*16 + lr)*KP + k*32 + lh*8];
          acc = mfma16(pa[k], bf, acc);
        }
        const f32x4 rs = *(const f32x4*)&sROW[wv*16 + lh*4];
        const float bv = nt2 ? bvt1 : bvt0;
        #pragma unroll
        for (int r = 0; r < 4; ++r)
          h1r[p][nt2][r] = (f16)lrelu(acc[r]*frcp(rs[r]) + bv);
      }
    }
    // --- dump h1 regs -> sXm rows of own m-tile (read back only by this wave) ---
    #pragma unroll
    for (int p = 0; p < 5; ++p) {
      #pragma unroll
      for (int nt2 = 0; nt2 < 2; ++nt2) {
        const int fl = nt2*16 + lr;
        if (fl < NF1) {
          #pragma unroll
          for (int r = 0; r < 4; ++r) {
            const int mg = wv*16 + lh*4 + r;
            if (mg < NV) sXm[mg*KP + p*NF1 + fl] = h1r[p][nt2][r];
          }
        }
      }
    }
    // --- feats2 = h1 @ W2aug : cols 0..8 feats2, cols 9..14 logits ---
    {
      f32x4 acc = {0.f,0.f,0.f,0.f};
      #pragma unroll
      for (int k = 0; k < 4; ++k) {
        f16x8 af = *(const f16x8*)&sXm[(wv*16 + lr)*KP + k*32 + lh*8];
        f16x8 bf = *(const f16x8*)&W2tg[lr*KP + k*32 + lh*8];
        acc = mfma16(af, bf, acc);
      }
      const int mg0 = wv*16 + lh*4;
      if (lr < 9) {
        #pragma unroll
        for (int r = 0; r < 4; ++r) {
          const int mg = mg0 + r;
          if (mg < NV) sF2t[lr*KP + mg] = (f16)acc[r];
        }
      } else if (lr < 12) {
        *(f32x4*)&sES2[(lr-9)*112 + mg0] = acc;
      } else if (lr < 15) {
        *(f32x4*)&sEN2[(lr-12)*128 + mg0] = acc;
      }
    }
  }
  __syncthreads();   // (3) feats2^T + L2 logits visible (cross-wave)

  // ============ L2 passes: P2 in registers, per-head accumulators ==========
  f32x4 a2_0 = {0.f,0.f,0.f,0.f};
  f32x4 a2_1 = {0.f,0.f,0.f,0.f};
  f32x4 a2_2 = {0.f,0.f,0.f,0.f};
  if (wv < 7) {
    #pragma unroll
    for (int g = 0; g < 3; ++g) {
      const float es = sES2[g*112 + row];
      float psum = 0.f;
      #pragma unroll
      for (int k = 0; k < 4; ++k) {
        const int cb = k*32 + lh*8;
        const f32x4 enA = *(const f32x4*)&sEN2[g*128 + cb];
        const f32x4 enB = *(const f32x4*)&sEN2[g*128 + cb + 4];
        const unsigned bits = (unsigned)(((cb & 64) ? am1 : am0) >> (cb & 63)) & 0xFFu;
        float e[8];
        #pragma unroll
        for (int j = 0; j < 8; ++j) {
          float v = es + ((j < 4) ? enA[j] : enB[j-4]);
          v = fmaxf(v, LALPHA*v);
          v = (bits & (1u << j)) ? v : -1e30f;
          e[j] = expm4(v);
          psum += e[j];
        }
        union { f16x8 v8; h16x2 h2[4]; } u;
        u.h2[0] = __builtin_amdgcn_cvt_pkrtz(e[0], e[1]);
        u.h2[1] = __builtin_amdgcn_cvt_pkrtz(e[2], e[3]);
        u.h2[2] = __builtin_amdgcn_cvt_pkrtz(e[4], e[5]);
        u.h2[3] = __builtin_amdgcn_cvt_pkrtz(e[6], e[7]);
        pa[k] = u.v8;
      }
      psum += __shfl_xor(psum, 16);
      psum += __shfl_xor(psum, 32);
      if (lh == 0) sROW2[g*112 + row] = psum;   // same-wave handoff
      const int brow = (lr < NF2) ? (g*NF2 + lr) : 15;   // row 15 stays zero
      #pragma unroll
      for (int k = 0; k < 4; ++k) {
        f16x8 bf = *(const f16x8*)&sF2t[brow*KP + k*32 + lh*8];
        if (g == 0)      a2_0 = mfma16(pa[k], bf, a2_0);
        else if (g == 1) a2_1 = mfma16(pa[k], bf, a2_1);
        else             a2_2 = mfma16(pa[k], bf, a2_2);
      }
    }
    // --- t[n] = sigmoid( lrelu(mean_g(a2_g/sum_g) + b2) . fc1 ) ---
    const int mg0 = wv*16 + lh*4;
    const float fcv = (lr < NF2) ? fc1w[lr] : 0.f;
    const float b2v = (lr < NF2) ? b2[lr]  : 0.f;
    const f32x4 rs0 = *(const f32x4*)&sROW2[0*112 + mg0];
    const f32x4 rs1 = *(const f32x4*)&sROW2[1*112 + mg0];
    const f32x4 rs2 = *(const f32x4*)&sROW2[2*112 + mg0];
    #pragma unroll
    for (int r = 0; r < 4; ++r) {
      const float hsum = a2_0[r]*frcp(rs0[r]) + a2_1[r]*frcp(rs1[r])
                       + a2_2[r]*frcp(rs2[r]);
      float hv = (lr < NF2) ? lrelu(hsum*(1.f/NH2) + b2v)*fcv : 0.f;
      hv += __shfl_xor(hv, 1);
      hv += __shfl_xor(hv, 2);
      hv += __shfl_xor(hv, 4);
      hv += __shfl_xor(hv, 8);
      if (lr == 0) {
        const int mg = mg0 + r;
        if (mg < NV) sT[mg] = sigm(hv);
      }
    }
  }
  __syncthreads();   // (4) sT complete; sF2t reads done
  // --- stage t16: t replicated across 16 rows (A-operand), zero-padded ---
  for (int i = tid; i < 16*KP; i += T1) {
    const int k = i % KP;
    t16[i] = (k < NV) ? (f16)sT[k] : (f16)0.f;
  }
  __syncthreads();   // (5)
  // --- s = t @ fc2 via MFMA (fc2^T f16 from global) ---
  if (wv < 7) {
    f32x4 acc = {0.f,0.f,0.f,0.f};
    #pragma unroll
    for (int k = 0; k < 4; ++k) {
      f16x8 af = *(const f16x8*)&t16[lr*KP + k*32 + lh*8];
      f16x8 bf = *(const f16x8*)&fc2tg[(wv*16 + lr)*KP + k*32 + lh*8];
      acc = mfma16(af, bf, acc);
    }
    const int col = wv*16 + lr;
    if (lh == 0 && col < NV) sS[col] = acc[0];
  }
  __syncthreads();   // (6)
  // --- out[b] = sum_m t[m]*softmax(s)[m] ---
  if (wv == 0) {
    const float s0 = sS[lane];
    const float s1 = (64+lane < NV) ? sS[64+lane] : -1e38f;
    const float mx = wmax(fmaxf(s0, s1));
    const float p0 = __expf(s0 - mx);
    const float p1 = (64+lane < NV) ? __expf(s1 - mx) : 0.f;
    const float sum = wsum(p0 + p1);
    float val = sT[lane]*p0 + ((64+lane < NV) ? sT[64+lane]*p1 : 0.f);
    val = wsum(val);
    if (lane == 0) out[b] = val*frcp(sum);
  }
}

extern "C" void kernel_launch(void* const* d_in, const int* in_sizes, int n_in,
                              void* d_out, int out_size, void* d_ws, size_t ws_size,
                              hipStream_t stream) {
  const float* X   = (const float*)d_in[0];
  const float* A   = (const float*)d_in[1];
  const float* M   = (const float*)d_in[2];
  const float* W1  = (const float*)d_in[3];
  const float* as1 = (const float*)d_in[4];
  const float* an1 = (const float*)d_in[5];
  const float* b1  = (const float*)d_in[6];
  const float* W2  = (const float*)d_in[7];
  const float* as2 = (const float*)d_in[8];
  const float* an2 = (const float*)d_in[9];
  const float* b2  = (const float*)d_in[10];
  const float* fc1 = (const float*)d_in[11];
  const float* fc2 = (const float*)d_in[12];
  float* out = (float*)d_out;

  // ws: Msig f32[12100] | W1tg f16[144*136] | W2tg f16[16*136] | fc2tg f16[112*136]
  float* Msig = (float*)d_ws;
  f16* W1tg  = (f16*)((char*)d_ws + 48400);
  f16* W2tg  = (f16*)((char*)d_ws + 48400 + W1ROWS*KP*2);
  f16* fc2tg = (f16*)((char*)d_ws + 48400 + W1ROWS*KP*2 + 16*KP*2);

  const int pre_items = NN + W1ROWS*KP + 16*KP + 112*KP;
  precomp_kernel<<<(pre_items + 255)/256, 256, 0, stream>>>(
      M, W1, as1, an1, W2, as2, an2, fc2, Msig, W1tg, W2tg, fc2tg);
  gat_fused<<<NB, T1, 0, stream>>>(X, A, Msig, W1tg, b1, W2tg,
                                   b2, fc1, fc2tg, out);
}